// Round 11
// baseline (1290.604 us; speedup 1.0000x reference)
//
#include <hip/hip_runtime.h>
#include <hip/hip_bf16.h>
#include <stdint.h>

// GRU sequence decoder, fused. B=32768, H=L=512, VOCAB=10, SEQ=6.
// R11 = R10 (573us) + two levers:
//  1) k-major padded LDS layout: h stored as 64 chunks of (8 bf16 x 64 rows),
//     chunk stride 1040B (16B pad kills the 1024B bank degeneracy).
//     ds_read addr = lane_base + kk*4160 + bt*256 -> ALL immediate offsets,
//     no XOR/add per read (R10 swizzle collided with kk bits -> VALU-bound),
//     zero bank conflicts (16-lane groups read 256B contiguous).
//  2) gi held in REGISTERS (gireg[4][3][4] bf16x4 = 96 VGPR, statically
//     indexed): gi ws buffer + 96MB write + 576MB re-reads + epilogue global
//     stall all deleted. Budget: __launch_bounds__(512,1) -> 256 regs, 2
//     waves/SIMD (=512-reg SIMD pool), 1 block/CU by design (R7/R8: second
//     8-wave block never co-resides).
// Kept from R10: h double-buffered in LDS (one barrier/step), 8 waves, wave
// owns jtiles [wq*4,wq*4+4) x 4 btiles, A=weight frag / B=h frag, weights
// pre-packed frag-order (L2-resident), logits on waves 0-3 post-barrier.

typedef __bf16 bf16_t;
typedef bf16_t bf16x8 __attribute__((ext_vector_type(8)));
typedef bf16_t bf16x4 __attribute__((ext_vector_type(4)));
typedef float  f32x4  __attribute__((ext_vector_type(4)));
typedef float  f32x2  __attribute__((ext_vector_type(2)));

#define THREADS 512
#define BM      64
#define NBLK    512
#define NSTEP   6
#define CH      1040              // chunk stride bytes (1024 + 16 pad)
#define BUFB    (64 * CH)         // one h buffer: 66560 B

// ws layout (bytes) — weights only now
#define WIH_OFF 0u            // 96 nt * 16 kk * 64 lane * 16B = 1572864
#define WHH_OFF 1572864u
#define WOP_OFF 3145728u      // 16 kk * 64 lane * 16B = 16384

static __device__ __forceinline__ float sigm(float v) { return 1.0f / (1.0f + __expf(-v)); }
static __device__ __forceinline__ float tanhf_(float v) {
  v = fminf(fmaxf(v, -12.0f), 12.0f);
  float e = __expf(2.0f * v);
  return 1.0f - 2.0f / (e + 1.0f);
}
static __device__ __forceinline__ f32x4 up4(bf16x4 v) {
  f32x4 o; o[0] = (float)v[0]; o[1] = (float)v[1]; o[2] = (float)v[2]; o[3] = (float)v[3];
  return o;
}
static __device__ __forceinline__ bf16x4 pk4(f32x4 v) {
  bf16x4 o; o[0] = (bf16_t)v[0]; o[1] = (bf16_t)v[1]; o[2] = (bf16_t)v[2]; o[3] = (bf16_t)v[3];
  return o;
}

// Pack weights into MFMA A-frag order:
//   chunk[(nt*16 + kk)*64 + lane] = w[nt*16 + (lane&15)][kk*32 + (lane>>4)*8 .. +8]
__global__ void prep_kernel(const float* __restrict__ wih_f, const float* __restrict__ whh_f,
                            const float* __restrict__ wout_f,
                            bf16x8* __restrict__ wihPk, bf16x8* __restrict__ whhPk,
                            bf16x8* __restrict__ wopPk) {
  int c = blockIdx.x * 256 + threadIdx.x;
  int lane = c & 63, l15 = lane & 15, lk = (lane >> 4) & 3;
  if (c < 196608) {
    int cid = (c < 98304) ? c : c - 98304;
    const float* src = (c < 98304) ? wih_f : whh_f;
    bf16x8* dst = (c < 98304) ? wihPk : whhPk;
    int kk = (cid >> 6) & 15;
    int nt = cid >> 10;
    const float* p = src + (size_t)(nt * 16 + l15) * 512 + kk * 32 + lk * 8;
    bf16x8 o;
    #pragma unroll
    for (int i = 0; i < 8; ++i) o[i] = (bf16_t)p[i];
    dst[cid] = o;
  } else if (c < 197632) {
    int cid = c - 196608;          // vocab tile: 16 kk * 64 lane
    int kk = cid >> 6;
    bf16x8 o;
    if (l15 < 10) {
      const float* p = wout_f + (size_t)l15 * 512 + kk * 32 + lk * 8;
      #pragma unroll
      for (int i = 0; i < 8; ++i) o[i] = (bf16_t)p[i];
    } else {
      #pragma unroll
      for (int i = 0; i < 8; ++i) o[i] = (bf16_t)0.0f;
    }
    wopPk[cid] = o;
  }
}

__global__ __launch_bounds__(THREADS, 1) void gru_kernel(
    const float* __restrict__ x, const float* __restrict__ b_ih,
    const float* __restrict__ b_hh, const float* __restrict__ b_out,
    const bf16x8* __restrict__ wih, const bf16x8* __restrict__ whh,
    const bf16x8* __restrict__ wop, float* __restrict__ out) {
  // h buffers, k-major: chunk c (k in [c*8,c*8+8)) x 64 rows, 16B/row, stride
  // CH=1040. Step t reads cur, ds_writes nxt, one barrier, swap.
  __shared__ __align__(16) char hlds[2 * BUFB];

  const int tid   = (int)threadIdx.x;
  const int lane  = tid & 63;
  const int wq    = tid >> 6;      // 0..7: wave owns jtiles [wq*4, wq*4+4)
  const int l15   = lane & 15;
  const int lk    = lane >> 4;
  const int brow0 = (int)blockIdx.x * BM;

  char* cur = hlds;
  char* nxt = hlds + BUFB;

  // ---------------- phase 0: x -> bf16 -> cur (h0 = x), k-major ----------
  #pragma unroll
  for (int it = 0; it < 16; ++it) {
    int f4  = it * THREADS + tid;
    int row = f4 >> 7, c4 = f4 & 127;          // c4 = 4-float group (k = c4*4)
    float4 v = ((const float4*)(x + (size_t)(brow0 + row) * 512))[c4];
    bf16x4 h4 = { (bf16_t)v.x, (bf16_t)v.y, (bf16_t)v.z, (bf16_t)v.w };
    *(bf16x4*)(&cur[(c4 >> 1) * CH + row * 16 + (c4 & 1) * 8]) = h4;
  }
  __syncthreads();

  // gi in registers: gireg[p][g][bt], bf16x4 each (96 VGPR), static indexing.
  bf16x4 gireg[4][3][4];

  // ---------------- gi phase: gi = x @ w_ih^T + biases ----------------
  {
    const char* aB = cur + lk * CH + l15 * 16;   // + kk*4160 + bt*256 (imm)
    #pragma unroll
    for (int p = 0; p < 4; ++p) {
      const int jt = wq * 4 + p;
      f32x4 acc[3][4];
      #pragma unroll
      for (int g = 0; g < 3; ++g)
        #pragma unroll
        for (int bt = 0; bt < 4; ++bt) acc[g][bt] = (f32x4){0.f, 0.f, 0.f, 0.f};

      #pragma unroll 4
      for (int kk = 0; kk < 16; ++kk) {
        bf16x8 hf[4];
        #pragma unroll
        for (int bt = 0; bt < 4; ++bt)
          hf[bt] = *(const bf16x8*)(aB + kk * 4160 + bt * 256);
        #pragma unroll
        for (int g = 0; g < 3; ++g) {
          bf16x8 wf = wih[((g * 32 + jt) * 16 + kk) * 64 + lane];
          #pragma unroll
          for (int bt = 0; bt < 4; ++bt)
            acc[g][bt] = __builtin_amdgcn_mfma_f32_16x16x32_bf16(wf, hf[bt], acc[g][bt], 0, 0, 0);
        }
      }
      int j = jt * 16 + lk * 4;
      f32x4 b0 = *(const f32x4*)(b_ih + j) + *(const f32x4*)(b_hh + j);
      f32x4 b1 = *(const f32x4*)(b_ih + 512 + j) + *(const f32x4*)(b_hh + 512 + j);
      f32x4 b2 = *(const f32x4*)(b_ih + 1024 + j);   // b_hh_n stays separate (x r)
      #pragma unroll
      for (int bt = 0; bt < 4; ++bt) {
        gireg[p][0][bt] = pk4(acc[0][bt] + b0);
        gireg[p][1][bt] = pk4(acc[1][bt] + b1);
        gireg[p][2][bt] = pk4(acc[2][bt] + b2);
      }
    }
  }

  // ---------------- 6 recurrent steps (one barrier each) ----------------
  for (int t = 0; t < NSTEP; ++t) {
    const char* aB = cur + lk * CH + l15 * 16;
    #pragma unroll
    for (int p = 0; p < 4; ++p) {
      const int jt = wq * 4 + p;

      f32x4 acc[3][4];
      #pragma unroll
      for (int g = 0; g < 3; ++g)
        #pragma unroll
        for (int bt = 0; bt < 4; ++bt) acc[g][bt] = (f32x4){0.f, 0.f, 0.f, 0.f};

      #pragma unroll 4
      for (int kk = 0; kk < 16; ++kk) {
        bf16x8 hf[4];
        #pragma unroll
        for (int bt = 0; bt < 4; ++bt)
          hf[bt] = *(const bf16x8*)(aB + kk * 4160 + bt * 256);
        #pragma unroll
        for (int g = 0; g < 3; ++g) {
          bf16x8 wf = whh[((g * 32 + jt) * 16 + kk) * 64 + lane];
          #pragma unroll
          for (int bt = 0; bt < 4; ++bt)
            acc[g][bt] = __builtin_amdgcn_mfma_f32_16x16x32_bf16(wf, hf[bt], acc[g][bt], 0, 0, 0);
        }
      }
      // GRU cell epilogue: gi from regs; h_old from LDS; h_new ds_write -> nxt.
      {
        int j = jt * 16 + lk * 4;
        f32x4 bn4 = *(const f32x4*)(b_hh + 1024 + j);
        // h j-slice lives at chunk jt*2 + (lk>>1), byte (lk&1)*8
        const int cof = jt * 2 * CH + (lk >> 1) * CH + l15 * 16 + (lk & 1) * 8;
        #pragma unroll
        for (int bt = 0; bt < 4; ++bt) {
          f32x4 gr  = up4(gireg[p][0][bt]);
          f32x4 gz  = up4(gireg[p][1][bt]);
          f32x4 gn  = up4(gireg[p][2][bt]);
          f32x4 hov = up4(*(const bf16x4*)(cur + cof + bt * 256));
          f32x4 hv;
          #pragma unroll
          for (int r = 0; r < 4; ++r) {
            float rv = sigm(gr[r] + acc[0][bt][r]);
            float zv = sigm(gz[r] + acc[1][bt][r]);
            float nv = tanhf_(gn[r] + rv * (acc[2][bt][r] + bn4[r]));
            hv[r] = (1.0f - zv) * nv + zv * hov[r];
          }
          *(bf16x4*)(nxt + cof + bt * 256) = pk4(hv);
        }
      }
    }
    __syncthreads();   // h_{t+1} writes drained & visible; h_t reads all done

    { char* tmp = cur; cur = nxt; nxt = tmp; }   // cur = h_{t+1}

    // logits_t = h_{t+1} @ w_out^T + b_out ; waves 0..3 each own one btile.
    // Concurrent with other waves' next-step k-loop (both only read cur).
    if (wq < 4) {
      const char* aL = cur + lk * CH + l15 * 16 + wq * 256;
      f32x4 lacc = (f32x4){0.f, 0.f, 0.f, 0.f};
      #pragma unroll 4
      for (int kk = 0; kk < 16; ++kk) {
        bf16x8 hf = *(const bf16x8*)(aL + kk * 4160);
        bf16x8 wf = wop[kk * 64 + lane];
        lacc = __builtin_amdgcn_mfma_f32_16x16x32_bf16(wf, hf, lacc, 0, 0, 0);
      }
      size_t ob = (size_t)(brow0 + wq * 16 + l15) * 60 + t * 10 + lk * 4;
      if (lk < 2) {
        f32x2 a = { lacc[0] + b_out[lk * 4 + 0], lacc[1] + b_out[lk * 4 + 1] };
        f32x2 b = { lacc[2] + b_out[lk * 4 + 2], lacc[3] + b_out[lk * 4 + 3] };
        *(f32x2*)(out + ob) = a;
        *(f32x2*)(out + ob + 2) = b;
      } else if (lk == 2) {
        f32x2 a = { lacc[0] + b_out[8], lacc[1] + b_out[9] };
        *(f32x2*)(out + ob) = a;
      }
    }
  }
}

extern "C" void kernel_launch(void* const* d_in, const int* in_sizes, int n_in,
                              void* d_out, int out_size, void* d_ws, size_t ws_size,
                              hipStream_t stream) {
  const float* x     = (const float*)d_in[0];
  const float* wih_f = (const float*)d_in[1];
  const float* whh_f = (const float*)d_in[2];
  const float* b_ih  = (const float*)d_in[3];
  const float* b_hh  = (const float*)d_in[4];
  const float* wout  = (const float*)d_in[5];
  const float* b_out = (const float*)d_in[6];

  char* ws = (char*)d_ws;
  bf16x8* wihPk = (bf16x8*)(ws + WIH_OFF);
  bf16x8* whhPk = (bf16x8*)(ws + WHH_OFF);
  bf16x8* wopPk = (bf16x8*)(ws + WOP_OFF);

  prep_kernel<<<772, 256, 0, stream>>>(wih_f, whh_f, wout, wihPk, whhPk, wopPk);
  gru_kernel<<<NBLK, THREADS, 0, stream>>>(x, b_ih, b_hh, b_out,
                                           wihPk, whhPk, wopPk, (float*)d_out);
}